// Round 1
// baseline (6134.039 us; speedup 1.0000x reference)
//
#include <hip/hip_runtime.h>
#include <cstddef>
#include <cstdint>

#define LAT 512
#define HID 1024
#define NSLOT 16
#define NB 256
#define HOR 64

using short8  = __attribute__((ext_vector_type(8))) short;
using floatx4 = __attribute__((ext_vector_type(4))) float;

__device__ __forceinline__ float sigmoid_f(float x) { return 1.0f / (1.0f + __expf(-x)); }
__device__ __forceinline__ float tanh_f(float x) {
    float e = __expf(2.0f * x);
    return 1.0f - 2.0f / (e + 1.0f);
}
__device__ __forceinline__ unsigned short f2bf(float f) {
    union { float f; uint32_t u; } v; v.f = f;
    uint32_t u = v.u;
    return (unsigned short)((u + 0x7fffu + ((u >> 16) & 1u)) >> 16);
}
// async global->LDS, 16B per lane. LDS dest is wave-uniform base + lane*16.
__device__ __forceinline__ void async16(const void* g, void* l) {
    __builtin_amdgcn_global_load_lds(
        (const __attribute__((address_space(1))) unsigned int*)(unsigned long long)g,
        (__attribute__((address_space(3))) unsigned int*)(unsigned int)(unsigned long long)l,
        16, 0, 0);
}

// ---------------------------------------------------------------------------
// In-kernel tiled bf16 MFMA GEMM: acc += A[64 x 64*KIT] * W[BN x 64*KIT]^T
// TM=TN=2: 4 waves as 2x2, wave tile 32x32, BN=64.
// TM=TN=1: 4 waves M-stacked, wave tile 16x16, BN=16.
// Double-buffered global_load_lds staging with XOR-chunk swizzle
// (chunk c of row m stored at in-row slot c ^ (m&7)).
// ---------------------------------------------------------------------------
template<int TM, int TN, int KIT>
__device__ __forceinline__ void gemmrun(const unsigned short* __restrict__ A, int lda,
                                        const unsigned short* __restrict__ W, int ldw,
                                        short* As, short* Bs,
                                        floatx4 (&acc)[TM][TN], int w, int lane)
{
    const int r8 = lane >> 3;
    const int cx = (lane & 7) ^ r8;
    const int q  = lane >> 4;
    const int ml = lane & 15;
    constexpr int BN = (TN == 2) ? 64 : 16;
    const int wrow0 = (TN == 2) ? (w >> 1) * 32 : w * 16;
    const int wcol0 = (TN == 2) ? (w & 1) * 32 : 0;

    auto stage = [&](int k0, int buf) {
        short* ad = As + buf * 4096;
        short* bd = Bs + buf * 4096;
        #pragma unroll
        for (int u = 0; u < 2; ++u) {                    // A: 64 rows
            const int row = u * 32 + w * 8;
            async16(A + (size_t)(row + r8) * lda + k0 + cx * 8, ad + row * 64);
        }
        #pragma unroll
        for (int u = 0; u < (BN + 31) / 32; ++u) {       // W: BN rows
            const int row = u * 32 + w * 8;
            if (BN >= 32 || row < BN)
                async16(W + (size_t)(row + r8) * ldw + k0 + cx * 8, bd + row * 64);
        }
    };

    stage(0, 0);
    __syncthreads();                                     // drains vmcnt -> buf0 ready
    #pragma unroll 2
    for (int it = 0; it < KIT; ++it) {
        if (it + 1 < KIT) stage((it + 1) * 64, (it + 1) & 1);   // prefetch next tile
        const short* as = As + (it & 1) * 4096;
        const short* bs = Bs + (it & 1) * 4096;
        #pragma unroll
        for (int s = 0; s < 2; ++s) {
            short8 af[TM], bfr[TN];
            #pragma unroll
            for (int i = 0; i < TM; ++i) {
                const int m = wrow0 + i * 16 + ml;
                af[i] = *(const short8*)&as[(m * 8 + ((s * 4 + q) ^ (m & 7))) * 8];
            }
            #pragma unroll
            for (int j = 0; j < TN; ++j) {
                const int n = wcol0 + j * 16 + ml;
                bfr[j] = *(const short8*)&bs[(n * 8 + ((s * 4 + q) ^ (n & 7))) * 8];
            }
            #pragma unroll
            for (int i = 0; i < TM; ++i)
                #pragma unroll
                for (int j = 0; j < TN; ++j)
                    acc[i][j] = __builtin_amdgcn_mfma_f32_16x16x32_bf16(af[i], bfr[j], acc[i][j], 0, 0, 0);
        }
        __syncthreads();                                 // drain prefetch + protect buffers
    }
}

// ---------------------------------------------------------------------------
// Grid barrier: 8-way split arrival counters (256B apart) + gen flag.
// Release: __threadfence() (agent: waitcnt + L2 writeback) before arrival.
// Acquire: __threadfence() (L2/L1 invalidate) after observing release.
// Counters monotonic; round is 1-based and identical across all blocks.
// ---------------------------------------------------------------------------
__device__ __forceinline__ void gridbar(unsigned* bar, int round)
{
    __syncthreads();
    if (threadIdx.x == 0) {
        __threadfence();
        unsigned old = atomicAdd(&bar[(blockIdx.x & 7) << 6], 1u);
        if (old == (unsigned)round * 32u - 1u)           // last of this group's 32
            atomicAdd(&bar[512], 1u);
        while (__hip_atomic_load(&bar[512], __ATOMIC_RELAXED, __HIP_MEMORY_SCOPE_AGENT)
               < (unsigned)round * 8u)
            __builtin_amdgcn_s_sleep(2);
        __threadfence();
    }
    __syncthreads();
}

// LSTM pointwise on fused gate-interleaved accumulators.
// Block cols = packed p range [nb*64, nb*64+64): subtile g = gate (i,f,g,o), col = j.
// wn==0 waves hold gates i,f; wn==1 waves hold g,o -> exchange via LDS (ex = As).
// Cell state lives in cr[][] registers (wn==0 lanes) across all steps.
__device__ __forceinline__ void lstm_pw(const floatx4 (&acc)[2][2], float* ex,
                                        int wm, int wn, int q, int ml,
                                        float bI, float bF, float bG, float bO,
                                        float (&cr)[2][4], int brow0, int jj,
                                        unsigned short* hd1, int ld1,
                                        unsigned short* hd2, int ld2)
{
    if (wn == 1) {
        #pragma unroll
        for (int tm = 0; tm < 2; ++tm)
            #pragma unroll
            for (int tn = 0; tn < 2; ++tn)
                #pragma unroll
                for (int r = 0; r < 4; ++r)
                    ex[(wm * 32 + tm * 16 + q * 4 + r) * 32 + tn * 16 + ml] = acc[tm][tn][r];
    }
    __syncthreads();
    if (wn == 0) {
        #pragma unroll
        for (int tm = 0; tm < 2; ++tm)
            #pragma unroll
            for (int r = 0; r < 4; ++r) {
                const int row = wm * 32 + tm * 16 + q * 4 + r;
                const int b   = brow0 + row;
                const float gi = acc[tm][0][r] + bI;
                const float gf = acc[tm][1][r] + bF;
                const float gg = ex[row * 32 + ml] + bG;
                const float go = ex[row * 32 + 16 + ml] + bO;
                const float i_ = sigmoid_f(gi), f_ = sigmoid_f(gf);
                const float g_ = tanh_f(gg),    o_ = sigmoid_f(go);
                const float cn = f_ * cr[tm][r] + i_ * g_;
                cr[tm][r] = cn;
                const unsigned short hb = f2bf(o_ * tanh_f(cn));
                hd1[(size_t)b * ld1 + jj] = hb;
                if (hd2) hd2[(size_t)b * ld2 + jj] = hb;
            }
    }
}

struct RollArgs {
    const unsigned short* Wg0;   // [4096][1536] gate-interleaved packed
    const unsigned short* Wg1;   // [4096][2048] gate-interleaved packed
    const unsigned short* Wo1;   // [1024][1024]
    const unsigned short* Wo2;   // [512][1024]
    const float* bc0;            // [4096] packed combined bias (b_ih+b_hh)
    const float* bc1;            // [4096]
    const float* ob1;            // [1024]
    const float* ob2;            // [512]
    unsigned short* xh0;         // 2 x [NB][LAT+HID] ping-pong
    unsigned short* hh1;         // 2 x [NB][2*HID]   ping-pong
    unsigned short* tbuf;        // [NB][HID]
    float* out;                  // [NB][HOR][LAT]
    unsigned* bar;
};

// ---------------------------------------------------------------------------
// Persistent cooperative rollout: 64 steps x 4 grid-synced phases.
// 256 blocks (1/CU) x 256 threads. XCD-grouped tile map: x = blk&7 selects
// XCD-local weight slice; 4 M-blocks sharing a slice sit on the same XCD.
// ---------------------------------------------------------------------------
__global__ __launch_bounds__(256)
void rollout(RollArgs a)
{
    __shared__ __attribute__((aligned(16))) short As[2 * 4096];
    __shared__ __attribute__((aligned(16))) short Bs[2 * 4096];

    const int t    = threadIdx.x;
    const int lane = t & 63;
    const int w    = t >> 6;
    const int q    = lane >> 4;
    const int ml   = lane & 15;
    const int wm   = w >> 1, wn = w & 1;

    const int blk = blockIdx.x;
    const int x   = blk & 7;
    const int tt  = blk >> 3;
    const int mb  = tt & 3;          // M tile (64 rows)
    const int nbo = tt >> 2;         // 0..7
    const int nb  = x * 8 + nbo;     // 0..63 : N tile for gates (64 packed) / op1 (16)
    const int jj  = nb * 16 + ml;    // feature col for gates / op1
    // P4 map (blocks 0..127): nb4 in 0..31
    const int nbo4 = (tt >> 2) & 3;
    const int nb4  = x * 4 + nbo4;
    const int n4   = nb4 * 16 + ml;

    // hoisted biases (layout constant across steps)
    const float bI0 = a.bc0[nb * 64 + ml],      bF0 = a.bc0[nb * 64 + 16 + ml];
    const float bG0 = a.bc0[nb * 64 + 32 + ml], bO0 = a.bc0[nb * 64 + 48 + ml];
    const float bI1 = a.bc1[nb * 64 + ml],      bF1 = a.bc1[nb * 64 + 16 + ml];
    const float bG1 = a.bc1[nb * 64 + 32 + ml], bO1 = a.bc1[nb * 64 + 48 + ml];
    const float bv3 = a.ob1[jj];
    const float bv4 = (blk < 128) ? a.ob2[n4] : 0.f;

    float c0r[2][4] = {};            // cell states live in registers all 64 steps
    float c1r[2][4] = {};
    float* ex = (float*)As;

    const floatx4 zf = {0.f, 0.f, 0.f, 0.f};
    floatx4 acc2[2][2];
    floatx4 acc1[1][1];
    int round = 0;

    for (int step = 0; step < HOR; ++step) {
        unsigned short* xh_r = a.xh0 + (size_t)(step & 1) * NB * (LAT + HID);
        unsigned short* xh_w = a.xh0 + (size_t)((step + 1) & 1) * NB * (LAT + HID);
        unsigned short* hh_r = a.hh1 + (size_t)(step & 1) * NB * (2 * HID);
        unsigned short* hh_w = a.hh1 + (size_t)((step + 1) & 1) * NB * (2 * HID);

        // ---- P1: gates0 = [x|h0] @ Wg0p^T, fused pw -> h0 ----
        acc2[0][0] = zf; acc2[0][1] = zf; acc2[1][0] = zf; acc2[1][1] = zf;
        gemmrun<2, 2, (LAT + HID) / 64>(
            xh_r + (size_t)(mb * 64) * (LAT + HID), LAT + HID,
            a.Wg0 + (size_t)(nb * 64) * (LAT + HID), LAT + HID,
            As, Bs, acc2, w, lane);
        lstm_pw(acc2, ex, wm, wn, q, ml, bI0, bF0, bG0, bO0, c0r, mb * 64, jj,
                xh_w + LAT, LAT + HID,       // h0 -> next-step x|h0 buffer
                hh_r, 2 * HID);              // h0 -> this-step h0|h1 buffer
        gridbar(a.bar, ++round);

        // ---- P2: gates1 = [h0|h1] @ Wg1p^T, fused pw -> h1 ----
        acc2[0][0] = zf; acc2[0][1] = zf; acc2[1][0] = zf; acc2[1][1] = zf;
        gemmrun<2, 2, (2 * HID) / 64>(
            hh_r + (size_t)(mb * 64) * (2 * HID), 2 * HID,
            a.Wg1 + (size_t)(nb * 64) * (2 * HID), 2 * HID,
            As, Bs, acc2, w, lane);
        lstm_pw(acc2, ex, wm, wn, q, ml, bI1, bF1, bG1, bO1, c1r, mb * 64, jj,
                hh_w + HID, 2 * HID,         // h1 -> next-step h0|h1 buffer
                nullptr, 0);
        gridbar(a.bar, ++round);

        // ---- P3: t = relu(h1 @ Wo1^T + b1) -> tbuf ----
        acc1[0][0] = zf;
        gemmrun<1, 1, HID / 64>(
            hh_w + (size_t)(mb * 64) * (2 * HID) + HID, 2 * HID,
            a.Wo1 + (size_t)(nb * 16) * HID, HID,
            As, Bs, acc1, w, lane);
        {
            #pragma unroll
            for (int r = 0; r < 4; ++r) {
                const int b = mb * 64 + w * 16 + q * 4 + r;
                const float v = fmaxf(acc1[0][0][r] + bv3, 0.f);
                a.tbuf[(size_t)b * HID + jj] = f2bf(v);
            }
        }
        gridbar(a.bar, ++round);

        // ---- P4: pred = t @ Wo2^T + b2 -> out[:,step,:] fp32 AND next x bf16 ----
        if (blk < 128) {
            acc1[0][0] = zf;
            gemmrun<1, 1, HID / 64>(
                a.tbuf + (size_t)(mb * 64) * HID, HID,
                a.Wo2 + (size_t)(nb4 * 16) * HID, HID,
                As, Bs, acc1, w, lane);
            #pragma unroll
            for (int r = 0; r < 4; ++r) {
                const int b = mb * 64 + w * 16 + q * 4 + r;
                const float v = acc1[0][0][r] + bv4;
                a.out[(size_t)b * (HOR * LAT) + (size_t)step * LAT + n4] = v;
                xh_w[(size_t)b * (LAT + HID) + n4] = f2bf(v);
            }
        }
        gridbar(a.bar, ++round);
    }
}

// ---------------------------------------------------------------------------
// Weight packing
// ---------------------------------------------------------------------------
// Gate-interleaved pack: packed row p -> gate g=(p>>4)&3, col j=(p>>6)*16+(p&15),
// orig row = g*1024+j. K-concat [w_ih | w_hh]. Also emits combined packed bias.
__global__ __launch_bounds__(256)
void pack_gates(const float* __restrict__ w_ih, int Kih,
                const float* __restrict__ w_hh, int Khh,
                const float* __restrict__ b_ih, const float* __restrict__ b_hh,
                unsigned short* __restrict__ d, float* __restrict__ bc, int K)
{
    const int idx = blockIdx.x * 256 + threadIdx.x;
    if (idx >= 4096 * K) return;
    const int p = idx / K;
    const int k = idx - p * K;
    const int g = (p >> 4) & 3;
    const int j = ((p >> 6) << 4) | (p & 15);
    const int orow = g * 1024 + j;
    const float v = (k < Kih) ? w_ih[(size_t)orow * Kih + k]
                              : w_hh[(size_t)orow * Khh + (k - Kih)];
    d[idx] = f2bf(v);
    if (k == 0) bc[p] = b_ih[orow] + b_hh[orow];
}

// plain bf16 pack (optionally K-concatenated)
__global__ __launch_bounds__(256)
void pack2(const float* __restrict__ s1, int K1, const float* __restrict__ s2, int K2,
           unsigned short* __restrict__ d, int total, int K)
{
    const int idx = blockIdx.x * 256 + threadIdx.x;
    if (idx >= total) return;
    const int n = idx / K;
    const int k = idx - n * K;
    const float v = (k < K1) ? s1[(size_t)n * K1 + k] : s2[(size_t)n * K2 + (k - K1)];
    d[idx] = f2bf(v);
}

// ---------------------------------------------------------------------------
// fp32 prologue GEMM (attention + prior): small, runs once. C2 = bf16 copy.
// ---------------------------------------------------------------------------
template<int RELU>
__global__ __launch_bounds__(256)
void gemm_tn(const float* __restrict__ A1, int lda1,
             const float* __restrict__ W1, int ldw1, int K1,
             const float* __restrict__ A2, int lda2,
             const float* __restrict__ W2, int ldw2, int K2,
             const float* __restrict__ bias1,
             float* __restrict__ C, int ldc,
             unsigned short* __restrict__ C2, int ldc2,
             int M, int N)
{
    __shared__ float As[16][64];
    __shared__ float Ws[16][64];
    const int t   = threadIdx.x;
    const int bn0 = blockIdx.x * 64;
    const int bm0 = blockIdx.y * 64;
    const int tx  = t & 15;
    const int ty  = t >> 4;
    const int lr  = t >> 2;
    const int lc  = (t & 3) << 2;

    float acc[4][4] = {};

    for (int src = 0; src < 2; ++src) {
        const float* A = src ? A2 : A1;
        if (!A) continue;
        const float* W = src ? W2 : W1;
        const int lda = src ? lda2 : lda1;
        const int ldw = src ? ldw2 : ldw1;
        const int K   = src ? K2 : K1;
        for (int k0 = 0; k0 < K; k0 += 16) {
            float4 av = make_float4(0.f, 0.f, 0.f, 0.f);
            const int am = bm0 + lr;
            if (am < M) av = *(const float4*)(A + (size_t)am * lda + k0 + lc);
            const float4 wv = *(const float4*)(W + (size_t)(bn0 + lr) * ldw + k0 + lc);
            __syncthreads();
            As[lc + 0][lr] = av.x; As[lc + 1][lr] = av.y;
            As[lc + 2][lr] = av.z; As[lc + 3][lr] = av.w;
            Ws[lc + 0][lr] = wv.x; Ws[lc + 1][lr] = wv.y;
            Ws[lc + 2][lr] = wv.z; Ws[lc + 3][lr] = wv.w;
            __syncthreads();
            #pragma unroll
            for (int kk = 0; kk < 16; ++kk) {
                const float4 a = *(const float4*)&As[kk][ty * 4];
                const float4 b = *(const float4*)&Ws[kk][tx * 4];
                const float ar[4] = {a.x, a.y, a.z, a.w};
                const float br[4] = {b.x, b.y, b.z, b.w};
                #pragma unroll
                for (int i = 0; i < 4; ++i)
                    #pragma unroll
                    for (int j = 0; j < 4; ++j)
                        acc[i][j] = fmaf(ar[i], br[j], acc[i][j]);
            }
        }
    }

    const int n0 = bn0 + tx * 4;
    float bv[4] = {0.f, 0.f, 0.f, 0.f};
    if (bias1) {
        #pragma unroll
        for (int j = 0; j < 4; ++j) bv[j] += bias1[n0 + j];
    }
    #pragma unroll
    for (int i = 0; i < 4; ++i) {
        const int m = bm0 + ty * 4 + i;
        if (m < M) {
            float ov[4];
            #pragma unroll
            for (int j = 0; j < 4; ++j) {
                float v = acc[i][j] + bv[j];
                if (RELU) v = fmaxf(v, 0.f);
                ov[j] = v;
            }
            *(float4*)(C + (size_t)m * ldc + n0) = make_float4(ov[0], ov[1], ov[2], ov[3]);
            if (C2) {
                #pragma unroll
                for (int j = 0; j < 4; ++j)
                    C2[(size_t)m * ldc2 + n0 + j] = f2bf(ov[j]);
            }
        }
    }
}

__global__ __launch_bounds__(256)
void attn_kernel(const float* __restrict__ q, const float* __restrict__ k,
                 const float* __restrict__ v, float* __restrict__ ctx)
{
    __shared__ float red[NSLOT][4];
    __shared__ float wts[NSLOT];
    const int b = blockIdx.x;
    const int t = threadIdx.x;
    const float4 qv = *(const float4*)(q + (size_t)b * HID + t * 4);
    #pragma unroll
    for (int s = 0; s < NSLOT; ++s) {
        const float4 kv = *(const float4*)(k + (size_t)s * HID + t * 4);
        float p = qv.x * kv.x + qv.y * kv.y + qv.z * kv.z + qv.w * kv.w;
        #pragma unroll
        for (int off = 32; off > 0; off >>= 1) p += __shfl_down(p, off);
        if ((t & 63) == 0) red[s][t >> 6] = p;
    }
    __syncthreads();
    if (t == 0) {
        float sc[NSLOT];
        float mx = -1e30f;
        for (int s = 0; s < NSLOT; ++s) {
            sc[s] = (red[s][0] + red[s][1] + red[s][2] + red[s][3]) * 0.03125f;
            mx = fmaxf(mx, sc[s]);
        }
        float sum = 0.f;
        for (int s = 0; s < NSLOT; ++s) { const float e = __expf(sc[s] - mx); wts[s] = e; sum += e; }
        const float inv = 1.f / sum;
        for (int s = 0; s < NSLOT; ++s) wts[s] *= inv;
    }
    __syncthreads();
    float4 a = make_float4(0.f, 0.f, 0.f, 0.f);
    #pragma unroll
    for (int s = 0; s < NSLOT; ++s) {
        const float wv = wts[s];
        const float4 vv = *(const float4*)(v + (size_t)s * HID + t * 4);
        a.x += wv * vv.x; a.y += wv * vv.y; a.z += wv * vv.z; a.w += wv * vv.w;
    }
    *(float4*)(ctx + (size_t)b * HID + t * 4) = a;
}

extern "C" void kernel_launch(void* const* d_in, const int* in_sizes, int n_in,
                              void* d_out, int out_size, void* d_ws, size_t ws_size,
                              hipStream_t stream)
{
    const float* cs    = (const float*)d_in[0];
    const float* mem   = (const float*)d_in[2];
    const float* q_W   = (const float*)d_in[3];
    const float* q_b   = (const float*)d_in[4];
    const float* k_W   = (const float*)d_in[5];
    const float* k_b   = (const float*)d_in[6];
    const float* v_W   = (const float*)d_in[7];
    const float* v_b   = (const float*)d_in[8];
    const float* mo_W  = (const float*)d_in[9];
    const float* mo_b  = (const float*)d_in[10];
    const float* pg_W1 = (const float*)d_in[11];
    const float* pg_b1 = (const float*)d_in[12];
    const float* pg_W2 = (const float*)d_in[13];
    const float* pg_b2 = (const float*)d_in[14];
    const float* w_ih0 = (const float*)d_in[15];
    const float* w_hh0 = (const float*)d_in[16];
    const float* b_ih0 = (const float*)d_in[17];
    const float* b_hh0 = (const float*)d_in[18];
    const float* w_ih1 = (const float*)d_in[19];
    const float* w_hh1 = (const float*)d_in[20];
    const float* b_ih1 = (const float*)d_in[21];
    const float* b_hh1 = (const float*)d_in[22];
    const float* op_W1 = (const float*)d_in[23];
    const float* op_b1 = (const float*)d_in[24];
    const float* op_W2 = (const float*)d_in[25];
    const float* op_b2 = (const float*)d_in[26];

    float* out       = (float*)d_out;
    float* prior_out = out + (size_t)NB * HOR * LAT;

    char* base = (char*)d_ws;
    auto alloc = [&](size_t bytes) { char* r = base; base += (bytes + 255) & ~255ull; return r; };

    unsigned short* Wg0p = (unsigned short*)alloc((size_t)4 * HID * (LAT + HID) * 2);
    unsigned short* Wg1p = (unsigned short*)alloc((size_t)4 * HID * (2 * HID) * 2);
    unsigned short* Wo1  = (unsigned short*)alloc((size_t)HID * HID * 2);
    unsigned short* Wo2  = (unsigned short*)alloc((size_t)LAT * HID * 2);
    float*          bc0  = (float*)alloc((size_t)4 * HID * 4);
    float*          bc1  = (float*)alloc((size_t)4 * HID * 4);
    // zero-init region (contiguous, 256B-multiple sizes): xh0[2], hh1[2], bar
    unsigned short* xh0  = (unsigned short*)alloc((size_t)2 * NB * (LAT + HID) * 2);
    unsigned short* hh1  = (unsigned short*)alloc((size_t)2 * NB * (2 * HID) * 2);
    unsigned*       bar  = (unsigned*)alloc(4096);
    unsigned short* tbuf = (unsigned short*)alloc((size_t)NB * HID * 2);
    float* qbuf   = (float*)alloc((size_t)NB * HID * 4);
    float* kbuf   = (float*)alloc((size_t)NSLOT * HID * 4);
    float* vbuf   = (float*)alloc((size_t)NSLOT * HID * 4);
    float* ctxbuf = (float*)alloc((size_t)NB * HID * 4);
    float* ctxo   = (float*)alloc((size_t)NB * LAT * 4);
    float* pgh    = (float*)alloc((size_t)NB * HID * 4);

    const size_t zbytes = (size_t)2 * NB * (LAT + HID) * 2
                        + (size_t)2 * NB * (2 * HID) * 2 + 4096;
    hipMemsetAsync(xh0, 0, zbytes, stream);

    const dim3 blk(256);

    // ---- pack weights (gates: gate-interleaved + combined bias) ----
    {
        int tot = 4 * HID * (LAT + HID);
        pack_gates<<<dim3((tot + 255) / 256), blk, 0, stream>>>(
            w_ih0, LAT, w_hh0, HID, b_ih0, b_hh0, Wg0p, bc0, LAT + HID);
        tot = 4 * HID * (2 * HID);
        pack_gates<<<dim3((tot + 255) / 256), blk, 0, stream>>>(
            w_ih1, HID, w_hh1, HID, b_ih1, b_hh1, Wg1p, bc1, 2 * HID);
        tot = HID * HID;
        pack2<<<dim3((tot + 255) / 256), blk, 0, stream>>>(op_W1, HID, nullptr, 0, Wo1, tot, HID);
        tot = LAT * HID;
        pack2<<<dim3((tot + 255) / 256), blk, 0, stream>>>(op_W2, HID, nullptr, 0, Wo2, tot, HID);
    }

    // ---- prologue (fp32): attention read + prior ----
    gemm_tn<0><<<dim3(HID / 64, 1), blk, 0, stream>>>(
        mem, HID, k_W, HID, HID, nullptr, 0, nullptr, 0, 0,
        k_b, kbuf, HID, nullptr, 0, NSLOT, HID);
    gemm_tn<0><<<dim3(HID / 64, 1), blk, 0, stream>>>(
        mem, HID, v_W, HID, HID, nullptr, 0, nullptr, 0, 0,
        v_b, vbuf, HID, nullptr, 0, NSLOT, HID);
    gemm_tn<0><<<dim3(HID / 64, NB / 64), blk, 0, stream>>>(
        cs, LAT, q_W, LAT, LAT, nullptr, 0, nullptr, 0, 0,
        q_b, qbuf, HID, nullptr, 0, NB, HID);
    attn_kernel<<<dim3(NB), blk, 0, stream>>>(qbuf, kbuf, vbuf, ctxbuf);
    gemm_tn<0><<<dim3(LAT / 64, NB / 64), blk, 0, stream>>>(
        ctxbuf, HID, mo_W, HID, HID, nullptr, 0, nullptr, 0, 0,
        mo_b, ctxo, LAT, nullptr, 0, NB, LAT);
    gemm_tn<1><<<dim3(HID / 64, NB / 64), blk, 0, stream>>>(
        cs, LAT, pg_W1, HID, LAT, ctxo, LAT, pg_W1 + LAT, HID, LAT,
        pg_b1, pgh, HID, nullptr, 0, NB, HID);
    // prior -> fp32 output AND bf16 x0 into xh0 buffer 0 (first 512 cols)
    gemm_tn<0><<<dim3(LAT / 64, NB / 64), blk, 0, stream>>>(
        pgh, HID, pg_W2, HID, HID, nullptr, 0, nullptr, 0, 0,
        pg_b2, prior_out, LAT, xh0, LAT + HID, NB, LAT);

    // ---- persistent cooperative LSTM rollout ----
    RollArgs ra;
    ra.Wg0 = Wg0p; ra.Wg1 = Wg1p; ra.Wo1 = Wo1; ra.Wo2 = Wo2;
    ra.bc0 = bc0;  ra.bc1 = bc1;  ra.ob1 = op_b1; ra.ob2 = op_b2;
    ra.xh0 = xh0;  ra.hh1 = hh1;  ra.tbuf = tbuf;
    ra.out = out;  ra.bar = bar;
    void* kargs[] = { (void*)&ra };
    hipLaunchCooperativeKernel((const void*)rollout, dim3(256), dim3(256), kargs, 0, stream);
}

// Round 6
// 4538.048 us; speedup vs baseline: 1.3517x; 1.3517x over previous
//
#include <hip/hip_runtime.h>
#include <cstddef>
#include <cstdint>

#define LAT 512
#define HID 1024
#define NSLOT 16
#define NB 256
#define HOR 64

using short8  = __attribute__((ext_vector_type(8))) short;
using floatx4 = __attribute__((ext_vector_type(4))) float;

__device__ __forceinline__ float sigmoid_f(float x) { return 1.0f / (1.0f + __expf(-x)); }
__device__ __forceinline__ float tanh_f(float x) {
    float e = __expf(2.0f * x);
    return 1.0f - 2.0f / (e + 1.0f);
}
__device__ __forceinline__ unsigned short f2bf(float f) {
    union { float f; uint32_t u; } v; v.f = f;
    uint32_t u = v.u;
    return (unsigned short)((u + 0x7fffu + ((u >> 16) & 1u)) >> 16);
}
// async global->LDS, 16B per lane. LDS dest is wave-uniform base + lane*16.
__device__ __forceinline__ void async16(const void* g, void* l) {
    __builtin_amdgcn_global_load_lds(
        (const __attribute__((address_space(1))) unsigned int*)(unsigned long long)g,
        (__attribute__((address_space(3))) unsigned int*)(unsigned int)(unsigned long long)l,
        16, 0, 0);
}

// ---------------------------------------------------------------------------
// bf16 MFMA GEMM, one dispatch per op (kernel boundaries = all cross-tile
// ordering; NO grid barriers, NO counted vmcnt). 256 thr = 4 waves as 2x2:
// wave tile (BM/2)x(BN/2), 16x16x32 MFMA. K-loop = round-1-VERIFIED prefetch
// discipline: stage(it+1) issued before compute(it); trailing __syncthreads
// (compiler emits s_waitcnt vmcnt(0) lgkmcnt(0) + s_barrier) drains it.
// Staging/swizzle byte-identical to the 4453-us-verified kernel:
// chunk c of row m stored at in-row slot c ^ (m&7); fragment reads
// ds_read_b128 at slot (s*4+q)^(m&7).
// MODE 1: +bias, ReLU, bf16 store to Cb                      (op1)
// MODE 2: +bias, fp32 store to Cf AND bf16 store to Cb       (op2)
// MODE 3 (BN=128 only): fused LSTM pointwise. Gate-interleaved packed W means
//   thread fragment j = gate j (i,f,g,o) of feature jj -> thread-local pw:
//   c (fp32, Cf) read-modify-write (unique owner), h -> Cb (+optional Cb2).
// ---------------------------------------------------------------------------
template<int BM, int BN, int MODE>
__global__ __launch_bounds__(256)
void mfma_gemm(const unsigned short* __restrict__ A, int lda,
               const unsigned short* __restrict__ W, int ldw, int K,
               const float* __restrict__ bias,
               float* __restrict__ Cf, int ldc,
               unsigned short* __restrict__ Cb, int ldcb,
               unsigned short* __restrict__ Cb2, int ldcb2)
{
    constexpr int WM = BM / 2, WN = BN / 2, TM = WM / 16, TN = WN / 16;
    static_assert(MODE != 3 || TN == 4, "MODE 3 needs BN=128 (gate quad per thread)");
    __shared__ __attribute__((aligned(16))) short As[2][BM * 64];
    __shared__ __attribute__((aligned(16))) short Bs[2][BN * 64];

    const int t    = threadIdx.x;
    const int lane = t & 63;
    const int w    = t >> 6;
    const int wm   = w >> 1, wn = w & 1;
    const int m0   = blockIdx.y * BM;
    const int n0   = blockIdx.x * BN;

    const int r8 = lane >> 3;
    const int cx = (lane & 7) ^ r8;   // chunk c stored at in-row slot c^row
    const int q  = lane >> 4;
    const int ml = lane & 15;

    floatx4 acc[TM][TN];
    const floatx4 zf = {0.f, 0.f, 0.f, 0.f};
    #pragma unroll
    for (int i = 0; i < TM; ++i)
        #pragma unroll
        for (int j = 0; j < TN; ++j) acc[i][j] = zf;

    auto stage = [&](int k0, int buf) {
        #pragma unroll
        for (int u = 0; u < BM / 32; ++u) {
            const int row = w * (BM / 4) + u * 8;
            async16(A + (size_t)(m0 + row + r8) * lda + k0 + cx * 8, &As[buf][row * 64]);
        }
        #pragma unroll
        for (int u = 0; u < BN / 32; ++u) {
            const int row = w * (BN / 4) + u * 8;
            async16(W + (size_t)(n0 + row + r8) * ldw + k0 + cx * 8, &Bs[buf][row * 64]);
        }
    };

    stage(0, 0);
    __syncthreads();                                     // drains vmcnt -> buf0 ready
    const int nk = K / 64;
    for (int it = 0; it < nk; ++it) {
        if (it + 1 < nk) stage((it + 1) * 64, (it + 1) & 1);   // prefetch next tile
        const short* as = As[it & 1];
        const short* bs = Bs[it & 1];
        #pragma unroll
        for (int s = 0; s < 2; ++s) {
            short8 af[TM], bfr[TN];
            #pragma unroll
            for (int i = 0; i < TM; ++i) {
                const int m = wm * WM + i * 16 + ml;
                af[i] = *(const short8*)&as[(m * 8 + ((s * 4 + q) ^ (m & 7))) * 8];
            }
            #pragma unroll
            for (int j = 0; j < TN; ++j) {
                const int n = wn * WN + j * 16 + ml;
                bfr[j] = *(const short8*)&bs[(n * 8 + ((s * 4 + q) ^ (n & 7))) * 8];
            }
            #pragma unroll
            for (int i = 0; i < TM; ++i)
                #pragma unroll
                for (int j = 0; j < TN; ++j)
                    acc[i][j] = __builtin_amdgcn_mfma_f32_16x16x32_bf16(af[i], bfr[j], acc[i][j], 0, 0, 0);
        }
        __syncthreads();                                 // drain prefetch + protect bufs
    }

    // epilogue: C/D layout col = lane&15, row = q*4 + reg
    const int gmb = m0 + wm * WM + q * 4;
    if constexpr (MODE == 3) {
        // packed col base nn (multiple of 64): cols nn + g*16 + ml = gate g of
        // feature jj = (nn>>6)*16 + ml  (matches pack_gates layout)
        const int nn = n0 + wn * WN;
        const int jj = (nn >> 6) * 16 + ml;
        const float bI = bias[nn + ml],      bF = bias[nn + 16 + ml];
        const float bG = bias[nn + 32 + ml], bO = bias[nn + 48 + ml];
        #pragma unroll
        for (int i = 0; i < TM; ++i)
            #pragma unroll
            for (int r = 0; r < 4; ++r) {
                const int b = gmb + i * 16 + r;
                const float i_ = sigmoid_f(acc[i][0][r] + bI);
                const float f_ = sigmoid_f(acc[i][1][r] + bF);
                const float g_ = tanh_f(acc[i][2][r] + bG);
                const float o_ = sigmoid_f(acc[i][3][r] + bO);
                float* cp = Cf + (size_t)b * ldc + jj;   // unique owner thread
                const float cn = f_ * (*cp) + i_ * g_;
                *cp = cn;
                const unsigned short hb = f2bf(o_ * tanh_f(cn));
                Cb[(size_t)b * ldcb + jj] = hb;
                if (Cb2) Cb2[(size_t)b * ldcb2 + jj] = hb;
            }
    } else {
        const int gnb = n0 + wn * WN + ml;
        #pragma unroll
        for (int i = 0; i < TM; ++i)
            #pragma unroll
            for (int j = 0; j < TN; ++j) {
                const int gm = gmb + i * 16, gn = gnb + j * 16;
                const float bv = bias[gn];
                #pragma unroll
                for (int r = 0; r < 4; ++r) {
                    float v = acc[i][j][r] + bv;
                    if (MODE == 1) v = fmaxf(v, 0.f);
                    if (MODE == 2) Cf[(size_t)(gm + r) * ldc + gn] = v;
                    Cb[(size_t)(gm + r) * ldcb + gn] = f2bf(v);
                }
            }
    }
}

// ---------------------------------------------------------------------------
// Weight packing (both verified passing in earlier rounds)
// ---------------------------------------------------------------------------
// Gate-interleaved pack: packed row p -> gate g=(p>>4)&3, col j=(p>>6)*16+(p&15),
// orig row = g*1024+j. K-concat [w_ih | w_hh]. Also emits combined packed bias.
__global__ __launch_bounds__(256)
void pack_gates(const float* __restrict__ w_ih, int Kih,
                const float* __restrict__ w_hh, int Khh,
                const float* __restrict__ b_ih, const float* __restrict__ b_hh,
                unsigned short* __restrict__ d, float* __restrict__ bc, int K)
{
    const int idx = blockIdx.x * 256 + threadIdx.x;
    if (idx >= 4096 * K) return;
    const int p = idx / K;
    const int k = idx - p * K;
    const int g = (p >> 4) & 3;
    const int j = ((p >> 6) << 4) | (p & 15);
    const int orow = g * 1024 + j;
    const float v = (k < Kih) ? w_ih[(size_t)orow * Kih + k]
                              : w_hh[(size_t)orow * Khh + (k - Kih)];
    d[idx] = f2bf(v);
    if (k == 0) bc[p] = b_ih[orow] + b_hh[orow];
}

__global__ __launch_bounds__(256)
void pack2(const float* __restrict__ s1, int K1, const float* __restrict__ s2, int K2,
           unsigned short* __restrict__ d, int total, int K)
{
    const int idx = blockIdx.x * 256 + threadIdx.x;
    if (idx >= total) return;
    const int n = idx / K;
    const int k = idx - n * K;
    const float v = (k < K1) ? s1[(size_t)n * K1 + k] : s2[(size_t)n * K2 + (k - K1)];
    d[idx] = f2bf(v);
}

// ---------------------------------------------------------------------------
// fp32 prologue GEMM (attention + prior): small, runs once. C2 = bf16 copy.
// ---------------------------------------------------------------------------
template<int RELU>
__global__ __launch_bounds__(256)
void gemm_tn(const float* __restrict__ A1, int lda1,
             const float* __restrict__ W1, int ldw1, int K1,
             const float* __restrict__ A2, int lda2,
             const float* __restrict__ W2, int ldw2, int K2,
             const float* __restrict__ bias1,
             float* __restrict__ C, int ldc,
             unsigned short* __restrict__ C2, int ldc2,
             int M, int N)
{
    __shared__ float As[16][64];
    __shared__ float Ws[16][64];
    const int t   = threadIdx.x;
    const int bn0 = blockIdx.x * 64;
    const int bm0 = blockIdx.y * 64;
    const int tx  = t & 15;
    const int ty  = t >> 4;
    const int lr  = t >> 2;
    const int lc  = (t & 3) << 2;

    float acc[4][4] = {};

    for (int src = 0; src < 2; ++src) {
        const float* A = src ? A2 : A1;
        if (!A) continue;
        const float* W = src ? W2 : W1;
        const int lda = src ? lda2 : lda1;
        const int ldw = src ? ldw2 : ldw1;
        const int K   = src ? K2 : K1;
        for (int k0 = 0; k0 < K; k0 += 16) {
            float4 av = make_float4(0.f, 0.f, 0.f, 0.f);
            const int am = bm0 + lr;
            if (am < M) av = *(const float4*)(A + (size_t)am * lda + k0 + lc);
            const float4 wv = *(const float4*)(W + (size_t)(bn0 + lr) * ldw + k0 + lc);
            __syncthreads();
            As[lc + 0][lr] = av.x; As[lc + 1][lr] = av.y;
            As[lc + 2][lr] = av.z; As[lc + 3][lr] = av.w;
            Ws[lc + 0][lr] = wv.x; Ws[lc + 1][lr] = wv.y;
            Ws[lc + 2][lr] = wv.z; Ws[lc + 3][lr] = wv.w;
            __syncthreads();
            #pragma unroll
            for (int kk = 0; kk < 16; ++kk) {
                const float4 a = *(const float4*)&As[kk][ty * 4];
                const float4 b = *(const float4*)&Ws[kk][tx * 4];
                const float ar[4] = {a.x, a.y, a.z, a.w};
                const float br[4] = {b.x, b.y, b.z, b.w};
                #pragma unroll
                for (int i = 0; i < 4; ++i)
                    #pragma unroll
                    for (int j = 0; j < 4; ++j)
                        acc[i][j] = fmaf(ar[i], br[j], acc[i][j]);
            }
        }
    }

    const int n0 = bn0 + tx * 4;
    float bv[4] = {0.f, 0.f, 0.f, 0.f};
    if (bias1) {
        #pragma unroll
        for (int j = 0; j < 4; ++j) bv[j] += bias1[n0 + j];
    }
    #pragma unroll
    for (int i = 0; i < 4; ++i) {
        const int m = bm0 + ty * 4 + i;
        if (m < M) {
            float ov[4];
            #pragma unroll
            for (int j = 0; j < 4; ++j) {
                float v = acc[i][j] + bv[j];
                if (RELU) v = fmaxf(v, 0.f);
                ov[j] = v;
            }
            *(float4*)(C + (size_t)m * ldc + n0) = make_float4(ov[0], ov[1], ov[2], ov[3]);
            if (C2) {
                #pragma unroll
                for (int j = 0; j < 4; ++j)
                    C2[(size_t)m * ldc2 + n0 + j] = f2bf(ov[j]);
            }
        }
    }
}

__global__ __launch_bounds__(256)
void attn_kernel(const float* __restrict__ q, const float* __restrict__ k,
                 const float* __restrict__ v, float* __restrict__ ctx)
{
    __shared__ float red[NSLOT][4];
    __shared__ float wts[NSLOT];
    const int b = blockIdx.x;
    const int t = threadIdx.x;
    const float4 qv = *(const float4*)(q + (size_t)b * HID + t * 4);
    #pragma unroll
    for (int s = 0; s < NSLOT; ++s) {
        const float4 kv = *(const float4*)(k + (size_t)s * HID + t * 4);
        float p = qv.x * kv.x + qv.y * kv.y + qv.z * kv.z + qv.w * kv.w;
        #pragma unroll
        for (int off = 32; off > 0; off >>= 1) p += __shfl_down(p, off);
        if ((t & 63) == 0) red[s][t >> 6] = p;
    }
    __syncthreads();
    if (t == 0) {
        float sc[NSLOT];
        float mx = -1e30f;
        for (int s = 0; s < NSLOT; ++s) {
            sc[s] = (red[s][0] + red[s][1] + red[s][2] + red[s][3]) * 0.03125f;
            mx = fmaxf(mx, sc[s]);
        }
        float sum = 0.f;
        for (int s = 0; s < NSLOT; ++s) { const float e = __expf(sc[s] - mx); wts[s] = e; sum += e; }
        const float inv = 1.f / sum;
        for (int s = 0; s < NSLOT; ++s) wts[s] *= inv;
    }
    __syncthreads();
    float4 a = make_float4(0.f, 0.f, 0.f, 0.f);
    #pragma unroll
    for (int s = 0; s < NSLOT; ++s) {
        const float wv = wts[s];
        const float4 vv = *(const float4*)(v + (size_t)s * HID + t * 4);
        a.x += wv * vv.x; a.y += wv * vv.y; a.z += wv * vv.z; a.w += wv * vv.w;
    }
    *(float4*)(ctx + (size_t)b * HID + t * 4) = a;
}

extern "C" void kernel_launch(void* const* d_in, const int* in_sizes, int n_in,
                              void* d_out, int out_size, void* d_ws, size_t ws_size,
                              hipStream_t stream)
{
    const float* cs    = (const float*)d_in[0];
    const float* mem   = (const float*)d_in[2];
    const float* q_W   = (const float*)d_in[3];
    const float* q_b   = (const float*)d_in[4];
    const float* k_W   = (const float*)d_in[5];
    const float* k_b   = (const float*)d_in[6];
    const float* v_W   = (const float*)d_in[7];
    const float* v_b   = (const float*)d_in[8];
    const float* mo_W  = (const float*)d_in[9];
    const float* mo_b  = (const float*)d_in[10];
    const float* pg_W1 = (const float*)d_in[11];
    const float* pg_b1 = (const float*)d_in[12];
    const float* pg_W2 = (const float*)d_in[13];
    const float* pg_b2 = (const float*)d_in[14];
    const float* w_ih0 = (const float*)d_in[15];
    const float* w_hh0 = (const float*)d_in[16];
    const float* b_ih0 = (const float*)d_in[17];
    const float* b_hh0 = (const float*)d_in[18];
    const float* w_ih1 = (const float*)d_in[19];
    const float* w_hh1 = (const float*)d_in[20];
    const float* b_ih1 = (const float*)d_in[21];
    const float* b_hh1 = (const float*)d_in[22];
    const float* op_W1 = (const float*)d_in[23];
    const float* op_b1 = (const float*)d_in[24];
    const float* op_W2 = (const float*)d_in[25];
    const float* op_b2 = (const float*)d_in[26];

    float* out       = (float*)d_out;
    float* prior_out = out + (size_t)NB * HOR * LAT;

    char* base = (char*)d_ws;
    auto alloc = [&](size_t bytes) { char* r = base; base += (bytes + 255) & ~255ull; return r; };

    unsigned short* Wg0p = (unsigned short*)alloc((size_t)4 * HID * (LAT + HID) * 2);
    unsigned short* Wg1p = (unsigned short*)alloc((size_t)4 * HID * (2 * HID) * 2);
    unsigned short* Wo1  = (unsigned short*)alloc((size_t)HID * HID * 2);
    unsigned short* Wo2  = (unsigned short*)alloc((size_t)LAT * HID * 2);
    float*          bc0  = (float*)alloc((size_t)4 * HID * 4);
    float*          bc1  = (float*)alloc((size_t)4 * HID * 4);
    // zero-init region (contiguous, 256B-multiple sizes): xh0[2], hh1[2], c0, c1
    unsigned short* xh0  = (unsigned short*)alloc((size_t)2 * NB * (LAT + HID) * 2);
    unsigned short* hh1  = (unsigned short*)alloc((size_t)2 * NB * (2 * HID) * 2);
    float*          c0   = (float*)alloc((size_t)NB * HID * 4);
    float*          c1   = (float*)alloc((size_t)NB * HID * 4);
    unsigned short* tbuf = (unsigned short*)alloc((size_t)NB * HID * 2);
    float* qbuf   = (float*)alloc((size_t)NB * HID * 4);
    float* kbuf   = (float*)alloc((size_t)NSLOT * HID * 4);
    float* vbuf   = (float*)alloc((size_t)NSLOT * HID * 4);
    float* ctxbuf = (float*)alloc((size_t)NB * HID * 4);
    float* ctxo   = (float*)alloc((size_t)NB * LAT * 4);
    float* pgh    = (float*)alloc((size_t)NB * HID * 4);

    const size_t zbytes = (size_t)2 * NB * (LAT + HID) * 2
                        + (size_t)2 * NB * (2 * HID) * 2
                        + (size_t)NB * HID * 4 * 2;
    hipMemsetAsync(xh0, 0, zbytes, stream);

    const dim3 blk(256);

    // ---- pack weights (gates: gate-interleaved + combined bias) ----
    {
        int tot = 4 * HID * (LAT + HID);
        pack_gates<<<dim3((tot + 255) / 256), blk, 0, stream>>>(
            w_ih0, LAT, w_hh0, HID, b_ih0, b_hh0, Wg0p, bc0, LAT + HID);
        tot = 4 * HID * (2 * HID);
        pack_gates<<<dim3((tot + 255) / 256), blk, 0, stream>>>(
            w_ih1, HID, w_hh1, HID, b_ih1, b_hh1, Wg1p, bc1, 2 * HID);
        tot = HID * HID;
        pack2<<<dim3((tot + 255) / 256), blk, 0, stream>>>(op_W1, HID, nullptr, 0, Wo1, tot, HID);
        tot = LAT * HID;
        pack2<<<dim3((tot + 255) / 256), blk, 0, stream>>>(op_W2, HID, nullptr, 0, Wo2, tot, HID);
    }

    // ---- prologue (fp32): attention read + prior ----
    gemm_tn<0><<<dim3(HID / 64, 1), blk, 0, stream>>>(
        mem, HID, k_W, HID, HID, nullptr, 0, nullptr, 0, 0,
        k_b, kbuf, HID, nullptr, 0, NSLOT, HID);
    gemm_tn<0><<<dim3(HID / 64, 1), blk, 0, stream>>>(
        mem, HID, v_W, HID, HID, nullptr, 0, nullptr, 0, 0,
        v_b, vbuf, HID, nullptr, 0, NSLOT, HID);
    gemm_tn<0><<<dim3(HID / 64, NB / 64), blk, 0, stream>>>(
        cs, LAT, q_W, LAT, LAT, nullptr, 0, nullptr, 0, 0,
        q_b, qbuf, HID, nullptr, 0, NB, HID);
    attn_kernel<<<dim3(NB), blk, 0, stream>>>(qbuf, kbuf, vbuf, ctxbuf);
    gemm_tn<0><<<dim3(LAT / 64, NB / 64), blk, 0, stream>>>(
        ctxbuf, HID, mo_W, HID, HID, nullptr, 0, nullptr, 0, 0,
        mo_b, ctxo, LAT, nullptr, 0, NB, LAT);
    gemm_tn<1><<<dim3(HID / 64, NB / 64), blk, 0, stream>>>(
        cs, LAT, pg_W1, HID, LAT, ctxo, LAT, pg_W1 + LAT, HID, LAT,
        pg_b1, pgh, HID, nullptr, 0, NB, HID);
    // prior -> fp32 output AND bf16 x0 into xh0 buffer 0 (first 512 cols)
    gemm_tn<0><<<dim3(LAT / 64, NB / 64), blk, 0, stream>>>(
        pgh, HID, pg_W2, HID, HID, nullptr, 0, nullptr, 0, 0,
        pg_b2, prior_out, LAT, xh0, LAT + HID, NB, LAT);

    // ---- LSTM rollout: 4 dispatches/step, pw fused into gate GEMMs ----
    for (int step = 0; step < HOR; ++step) {
        const int cur = step & 1, nxt = cur ^ 1;
        unsigned short* xh_r = xh0 + (size_t)cur * NB * (LAT + HID);
        unsigned short* xh_w = xh0 + (size_t)nxt * NB * (LAT + HID);
        unsigned short* hh_c = hh1 + (size_t)cur * NB * (2 * HID);
        unsigned short* hh_n = hh1 + (size_t)nxt * NB * (2 * HID);

        // gates0 + pw: h0 -> hh_c[:, :HID] (this step) AND xh_w[:, LAT:] (next step)
        mfma_gemm<64, 128, 3><<<dim3(4 * HID / 128, NB / 64), blk, 0, stream>>>(
            xh_r, LAT + HID, Wg0p, LAT + HID, LAT + HID,
            bc0, c0, HID, hh_c, 2 * HID, xh_w + LAT, LAT + HID);
        // gates1 + pw: h1 -> hh_n[:, HID:] (read by op1 now, by gates1 next step)
        mfma_gemm<64, 128, 3><<<dim3(4 * HID / 128, NB / 64), blk, 0, stream>>>(
            hh_c, 2 * HID, Wg1p, 2 * HID, 2 * HID,
            bc1, c1, HID, hh_n + HID, 2 * HID, nullptr, 0);
        // op1: t = relu(h1 @ Wo1^T + b1) -> tbuf (bf16)
        mfma_gemm<64, 64, 1><<<dim3(HID / 64, NB / 64), blk, 0, stream>>>(
            hh_n + HID, 2 * HID, Wo1, HID, HID,
            op_b1, nullptr, 0, tbuf, HID, nullptr, 0);
        // op2: pred = t @ Wo2^T + b2 -> out[:,step,:] fp32 AND xh_w[:, :LAT] bf16
        mfma_gemm<64, 64, 2><<<dim3(LAT / 64, NB / 64), blk, 0, stream>>>(
            tbuf, HID, Wo2, HID, HID,
            op_b2, out + (size_t)step * LAT, HOR * LAT, xh_w, LAT + HID, nullptr, 0);
    }
}

// Round 7
// 3783.155 us; speedup vs baseline: 1.6214x; 1.1995x over previous
//
#include <hip/hip_runtime.h>
#include <cstddef>
#include <cstdint>

#define LAT 512
#define HID 1024
#define NSLOT 16
#define NB 256
#define HOR 64

using short8  = __attribute__((ext_vector_type(8))) short;
using floatx4 = __attribute__((ext_vector_type(4))) float;

__device__ __forceinline__ float sigmoid_f(float x) { return 1.0f / (1.0f + __expf(-x)); }
__device__ __forceinline__ float tanh_f(float x) {
    float e = __expf(2.0f * x);
    return 1.0f - 2.0f / (e + 1.0f);
}
__device__ __forceinline__ unsigned short f2bf(float f) {
    union { float f; uint32_t u; } v; v.f = f;
    uint32_t u = v.u;
    return (unsigned short)((u + 0x7fffu + ((u >> 16) & 1u)) >> 16);
}
// async global->LDS, 16B per lane. LDS dest is wave-uniform base + lane*16.
__device__ __forceinline__ void async16(const void* g, void* l) {
    __builtin_amdgcn_global_load_lds(
        (const __attribute__((address_space(1))) unsigned int*)(unsigned long long)g,
        (__attribute__((address_space(3))) unsigned int*)(unsigned int)(unsigned long long)l,
        16, 0, 0);
}

// ---------------------------------------------------------------------------
// bf16 MFMA GEMM, one dispatch per op; 512 threads = TWO K-TEAMS of 4 waves.
// Team tk covers K range [tk*K/2, (tk+1)*K/2) with the round-6-VERIFIED
// staging/swizzle/fragment code (chunk c of row m at in-row slot c^(m&7);
// drain-style double buffer: stage(it+1) before compute(it), trailing
// __syncthreads drains). Teams use disjoint LDS; sync counts are uniform
// across teams (same KIT). After the K-loops team 1 writes its accumulators
// thread-flat into its own dead Bs region; one block sync; team 0 adds and
// runs the verified epilogue. Halves the serial K-latency chain per block.
// MODE 1: +bias, ReLU, bf16 store to Cb                      (op1)
// MODE 2: +bias, fp32 store to Cf AND bf16 store to Cb       (op2)
// MODE 3 (BN=128): fused LSTM pointwise (gate-interleaved packed W):
//   thread fragment j = gate j (i,f,g,o) of feature jj; c (fp32, Cf) RMW.
// ---------------------------------------------------------------------------
template<int BM, int BN, int MODE>
__global__ __launch_bounds__(512)
void mfma_gemm(const unsigned short* __restrict__ A, int lda,
               const unsigned short* __restrict__ W, int ldw, int K,
               const float* __restrict__ bias,
               float* __restrict__ Cf, int ldc,
               unsigned short* __restrict__ Cb, int ldcb,
               unsigned short* __restrict__ Cb2, int ldcb2)
{
    constexpr int WM = BM / 2, WN = BN / 2, TM = WM / 16, TN = WN / 16;
    static_assert(MODE != 3 || TN == 4, "MODE 3 needs BN=128 (gate quad per thread)");
    __shared__ __attribute__((aligned(16))) short As[2][2][BM * 64];   // [team][buf]
    __shared__ __attribute__((aligned(16))) short Bs[2][2][BN * 64];

    const int t    = threadIdx.x;
    const int tk   = t >> 8;          // K-team 0/1
    const int lt   = t & 255;         // local thread within team
    const int lane = lt & 63;
    const int w    = lt >> 6;         // wave within team
    const int wm   = w >> 1, wn = w & 1;
    const int m0   = blockIdx.y * BM;
    const int n0   = blockIdx.x * BN;
    const int kb   = tk * (K / 2);    // team K base

    const int r8 = lane >> 3;
    const int cx = (lane & 7) ^ r8;   // chunk c stored at in-row slot c^row
    const int q  = lane >> 4;
    const int ml = lane & 15;

    floatx4 acc[TM][TN];
    const floatx4 zf = {0.f, 0.f, 0.f, 0.f};
    #pragma unroll
    for (int i = 0; i < TM; ++i)
        #pragma unroll
        for (int j = 0; j < TN; ++j) acc[i][j] = zf;

    auto stage = [&](int k0, int buf) {
        #pragma unroll
        for (int u = 0; u < BM / 32; ++u) {
            const int row = w * (BM / 4) + u * 8;
            async16(A + (size_t)(m0 + row + r8) * lda + k0 + cx * 8, &As[tk][buf][row * 64]);
        }
        #pragma unroll
        for (int u = 0; u < BN / 32; ++u) {
            const int row = w * (BN / 4) + u * 8;
            async16(W + (size_t)(n0 + row + r8) * ldw + k0 + cx * 8, &Bs[tk][buf][row * 64]);
        }
    };

    stage(kb, 0);
    __syncthreads();                                     // drains vmcnt -> buf0 ready
    const int nk = (K / 2) / 64;
    for (int it = 0; it < nk; ++it) {
        if (it + 1 < nk) stage(kb + (it + 1) * 64, (it + 1) & 1);   // prefetch next
        const short* as = As[tk][it & 1];
        const short* bs = Bs[tk][it & 1];
        #pragma unroll
        for (int s = 0; s < 2; ++s) {
            short8 af[TM], bfr[TN];
            #pragma unroll
            for (int i = 0; i < TM; ++i) {
                const int m = wm * WM + i * 16 + ml;
                af[i] = *(const short8*)&as[(m * 8 + ((s * 4 + q) ^ (m & 7))) * 8];
            }
            #pragma unroll
            for (int j = 0; j < TN; ++j) {
                const int n = wn * WN + j * 16 + ml;
                bfr[j] = *(const short8*)&bs[(n * 8 + ((s * 4 + q) ^ (n & 7))) * 8];
            }
            #pragma unroll
            for (int i = 0; i < TM; ++i)
                #pragma unroll
                for (int j = 0; j < TN; ++j)
                    acc[i][j] = __builtin_amdgcn_mfma_f32_16x16x32_bf16(af[i], bfr[j], acc[i][j], 0, 0, 0);
        }
        __syncthreads();                                 // drain prefetch + protect bufs
    }

    // cross-team reduction: team 1 -> its own (dead) Bs region, thread-flat.
    // sizes match exactly: 256 thr * TM*TN floatx4 = Bs[1] bytes for both configs.
    floatx4* ex = (floatx4*)&Bs[1][0][0];
    if (tk == 1) {
        #pragma unroll
        for (int i = 0; i < TM; ++i)
            #pragma unroll
            for (int j = 0; j < TN; ++j)
                ex[lt * (TM * TN) + i * TN + j] = acc[i][j];
    }
    __syncthreads();
    if (tk == 1) return;
    #pragma unroll
    for (int i = 0; i < TM; ++i)
        #pragma unroll
        for (int j = 0; j < TN; ++j) {
            const floatx4 o = ex[lt * (TM * TN) + i * TN + j];
            acc[i][j][0] += o[0]; acc[i][j][1] += o[1];
            acc[i][j][2] += o[2]; acc[i][j][3] += o[3];
        }

    // epilogue (team 0 only): C/D layout col = lane&15, row = q*4 + reg
    const int gmb = m0 + wm * WM + q * 4;
    if constexpr (MODE == 3) {
        const int nn = n0 + wn * WN;
        const int jj = (nn >> 6) * 16 + ml;
        const float bI = bias[nn + ml],      bF = bias[nn + 16 + ml];
        const float bG = bias[nn + 32 + ml], bO = bias[nn + 48 + ml];
        #pragma unroll
        for (int i = 0; i < TM; ++i)
            #pragma unroll
            for (int r = 0; r < 4; ++r) {
                const int b = gmb + i * 16 + r;
                const float i_ = sigmoid_f(acc[i][0][r] + bI);
                const float f_ = sigmoid_f(acc[i][1][r] + bF);
                const float g_ = tanh_f(acc[i][2][r] + bG);
                const float o_ = sigmoid_f(acc[i][3][r] + bO);
                float* cp = Cf + (size_t)b * ldc + jj;   // unique owner thread
                const float cn = f_ * (*cp) + i_ * g_;
                *cp = cn;
                const unsigned short hb = f2bf(o_ * tanh_f(cn));
                Cb[(size_t)b * ldcb + jj] = hb;
                if (Cb2) Cb2[(size_t)b * ldcb2 + jj] = hb;
            }
    } else {
        const int gnb = n0 + wn * WN + ml;
        #pragma unroll
        for (int i = 0; i < TM; ++i)
            #pragma unroll
            for (int j = 0; j < TN; ++j) {
                const int gm = gmb + i * 16, gn = gnb + j * 16;
                const float bv = bias[gn];
                #pragma unroll
                for (int r = 0; r < 4; ++r) {
                    float v = acc[i][j][r] + bv;
                    if (MODE == 1) v = fmaxf(v, 0.f);
                    if (MODE == 2) Cf[(size_t)(gm + r) * ldc + gn] = v;
                    Cb[(size_t)(gm + r) * ldcb + gn] = f2bf(v);
                }
            }
    }
}

// ---------------------------------------------------------------------------
// Weight packing (verified)
// ---------------------------------------------------------------------------
__global__ __launch_bounds__(256)
void pack_gates(const float* __restrict__ w_ih, int Kih,
                const float* __restrict__ w_hh, int Khh,
                const float* __restrict__ b_ih, const float* __restrict__ b_hh,
                unsigned short* __restrict__ d, float* __restrict__ bc, int K)
{
    const int idx = blockIdx.x * 256 + threadIdx.x;
    if (idx >= 4096 * K) return;
    const int p = idx / K;
    const int k = idx - p * K;
    const int g = (p >> 4) & 3;
    const int j = ((p >> 6) << 4) | (p & 15);
    const int orow = g * 1024 + j;
    const float v = (k < Kih) ? w_ih[(size_t)orow * Kih + k]
                              : w_hh[(size_t)orow * Khh + (k - Kih)];
    d[idx] = f2bf(v);
    if (k == 0) bc[p] = b_ih[orow] + b_hh[orow];
}

__global__ __launch_bounds__(256)
void pack2(const float* __restrict__ s1, int K1, const float* __restrict__ s2, int K2,
           unsigned short* __restrict__ d, int total, int K)
{
    const int idx = blockIdx.x * 256 + threadIdx.x;
    if (idx >= total) return;
    const int n = idx / K;
    const int k = idx - n * K;
    const float v = (k < K1) ? s1[(size_t)n * K1 + k] : s2[(size_t)n * K2 + (k - K1)];
    d[idx] = f2bf(v);
}

// ---------------------------------------------------------------------------
// fp32 prologue GEMM (attention + prior): small, runs once. C2 = bf16 copy.
// ---------------------------------------------------------------------------
template<int RELU>
__global__ __launch_bounds__(256)
void gemm_tn(const float* __restrict__ A1, int lda1,
             const float* __restrict__ W1, int ldw1, int K1,
             const float* __restrict__ A2, int lda2,
             const float* __restrict__ W2, int ldw2, int K2,
             const float* __restrict__ bias1,
             float* __restrict__ C, int ldc,
             unsigned short* __restrict__ C2, int ldc2,
             int M, int N)
{
    __shared__ float As[16][64];
    __shared__ float Ws[16][64];
    const int t   = threadIdx.x;
    const int bn0 = blockIdx.x * 64;
    const int bm0 = blockIdx.y * 64;
    const int tx  = t & 15;
    const int ty  = t >> 4;
    const int lr  = t >> 2;
    const int lc  = (t & 3) << 2;

    float acc[4][4] = {};

    for (int src = 0; src < 2; ++src) {
        const float* A = src ? A2 : A1;
        if (!A) continue;
        const float* W = src ? W2 : W1;
        const int lda = src ? lda2 : lda1;
        const int ldw = src ? ldw2 : ldw1;
        const int K   = src ? K2 : K1;
        for (int k0 = 0; k0 < K; k0 += 16) {
            float4 av = make_float4(0.f, 0.f, 0.f, 0.f);
            const int am = bm0 + lr;
            if (am < M) av = *(const float4*)(A + (size_t)am * lda + k0 + lc);
            const float4 wv = *(const float4*)(W + (size_t)(bn0 + lr) * ldw + k0 + lc);
            __syncthreads();
            As[lc + 0][lr] = av.x; As[lc + 1][lr] = av.y;
            As[lc + 2][lr] = av.z; As[lc + 3][lr] = av.w;
            Ws[lc + 0][lr] = wv.x; Ws[lc + 1][lr] = wv.y;
            Ws[lc + 2][lr] = wv.z; Ws[lc + 3][lr] = wv.w;
            __syncthreads();
            #pragma unroll
            for (int kk = 0; kk < 16; ++kk) {
                const float4 a = *(const float4*)&As[kk][ty * 4];
                const float4 b = *(const float4*)&Ws[kk][tx * 4];
                const float ar[4] = {a.x, a.y, a.z, a.w};
                const float br[4] = {b.x, b.y, b.z, b.w};
                #pragma unroll
                for (int i = 0; i < 4; ++i)
                    #pragma unroll
                    for (int j = 0; j < 4; ++j)
                        acc[i][j] = fmaf(ar[i], br[j], acc[i][j]);
            }
        }
    }

    const int n0 = bn0 + tx * 4;
    float bv[4] = {0.f, 0.f, 0.f, 0.f};
    if (bias1) {
        #pragma unroll
        for (int j = 0; j < 4; ++j) bv[j] += bias1[n0 + j];
    }
    #pragma unroll
    for (int i = 0; i < 4; ++i) {
        const int m = bm0 + ty * 4 + i;
        if (m < M) {
            float ov[4];
            #pragma unroll
            for (int j = 0; j < 4; ++j) {
                float v = acc[i][j] + bv[j];
                if (RELU) v = fmaxf(v, 0.f);
                ov[j] = v;
            }
            *(float4*)(C + (size_t)m * ldc + n0) = make_float4(ov[0], ov[1], ov[2], ov[3]);
            if (C2) {
                #pragma unroll
                for (int j = 0; j < 4; ++j)
                    C2[(size_t)m * ldc2 + n0 + j] = f2bf(ov[j]);
            }
        }
    }
}

__global__ __launch_bounds__(256)
void attn_kernel(const float* __restrict__ q, const float* __restrict__ k,
                 const float* __restrict__ v, float* __restrict__ ctx)
{
    __shared__ float red[NSLOT][4];
    __shared__ float wts[NSLOT];
    const int b = blockIdx.x;
    const int t = threadIdx.x;
    const float4 qv = *(const float4*)(q + (size_t)b * HID + t * 4);
    #pragma unroll
    for (int s = 0; s < NSLOT; ++s) {
        const float4 kv = *(const float4*)(k + (size_t)s * HID + t * 4);
        float p = qv.x * kv.x + qv.y * kv.y + qv.z * kv.z + qv.w * kv.w;
        #pragma unroll
        for (int off = 32; off > 0; off >>= 1) p += __shfl_down(p, off);
        if ((t & 63) == 0) red[s][t >> 6] = p;
    }
    __syncthreads();
    if (t == 0) {
        float sc[NSLOT];
        float mx = -1e30f;
        for (int s = 0; s < NSLOT; ++s) {
            sc[s] = (red[s][0] + red[s][1] + red[s][2] + red[s][3]) * 0.03125f;
            mx = fmaxf(mx, sc[s]);
        }
        float sum = 0.f;
        for (int s = 0; s < NSLOT; ++s) { const float e = __expf(sc[s] - mx); wts[s] = e; sum += e; }
        const float inv = 1.f / sum;
        for (int s = 0; s < NSLOT; ++s) wts[s] *= inv;
    }
    __syncthreads();
    float4 a = make_float4(0.f, 0.f, 0.f, 0.f);
    #pragma unroll
    for (int s = 0; s < NSLOT; ++s) {
        const float wv = wts[s];
        const float4 vv = *(const float4*)(v + (size_t)s * HID + t * 4);
        a.x += wv * vv.x; a.y += wv * vv.y; a.z += wv * vv.z; a.w += wv * vv.w;
    }
    *(float4*)(ctx + (size_t)b * HID + t * 4) = a;
}

extern "C" void kernel_launch(void* const* d_in, const int* in_sizes, int n_in,
                              void* d_out, int out_size, void* d_ws, size_t ws_size,
                              hipStream_t stream)
{
    const float* cs    = (const float*)d_in[0];
    const float* mem   = (const float*)d_in[2];
    const float* q_W   = (const float*)d_in[3];
    const float* q_b   = (const float*)d_in[4];
    const float* k_W   = (const float*)d_in[5];
    const float* k_b   = (const float*)d_in[6];
    const float* v_W   = (const float*)d_in[7];
    const float* v_b   = (const float*)d_in[8];
    const float* mo_W  = (const float*)d_in[9];
    const float* mo_b  = (const float*)d_in[10];
    const float* pg_W1 = (const float*)d_in[11];
    const float* pg_b1 = (const float*)d_in[12];
    const float* pg_W2 = (const float*)d_in[13];
    const float* pg_b2 = (const float*)d_in[14];
    const float* w_ih0 = (const float*)d_in[15];
    const float* w_hh0 = (const float*)d_in[16];
    const float* b_ih0 = (const float*)d_in[17];
    const float* b_hh0 = (const float*)d_in[18];
    const float* w_ih1 = (const float*)d_in[19];
    const float* w_hh1 = (const float*)d_in[20];
    const float* b_ih1 = (const float*)d_in[21];
    const float* b_hh1 = (const float*)d_in[22];
    const float* op_W1 = (const float*)d_in[23];
    const float* op_b1 = (const float*)d_in[24];
    const float* op_W2 = (const float*)d_in[25];
    const float* op_b2 = (const float*)d_in[26];

    float* out       = (float*)d_out;
    float* prior_out = out + (size_t)NB * HOR * LAT;

    char* base = (char*)d_ws;
    auto alloc = [&](size_t bytes) { char* r = base; base += (bytes + 255) & ~255ull; return r; };

    unsigned short* Wg0p = (unsigned short*)alloc((size_t)4 * HID * (LAT + HID) * 2);
    unsigned short* Wg1p = (unsigned short*)alloc((size_t)4 * HID * (2 * HID) * 2);
    unsigned short* Wo1  = (unsigned short*)alloc((size_t)HID * HID * 2);
    unsigned short* Wo2  = (unsigned short*)alloc((size_t)LAT * HID * 2);
    float*          bc0  = (float*)alloc((size_t)4 * HID * 4);
    float*          bc1  = (float*)alloc((size_t)4 * HID * 4);
    // zero-init region (contiguous, 256B-multiple sizes): xh0[2], hh1[2], c0, c1
    unsigned short* xh0  = (unsigned short*)alloc((size_t)2 * NB * (LAT + HID) * 2);
    unsigned short* hh1  = (unsigned short*)alloc((size_t)2 * NB * (2 * HID) * 2);
    float*          c0   = (float*)alloc((size_t)NB * HID * 4);
    float*          c1   = (float*)alloc((size_t)NB * HID * 4);
    unsigned short* tbuf = (unsigned short*)alloc((size_t)NB * HID * 2);
    float* qbuf   = (float*)alloc((size_t)NB * HID * 4);
    float* kbuf   = (float*)alloc((size_t)NSLOT * HID * 4);
    float* vbuf   = (float*)alloc((size_t)NSLOT * HID * 4);
    float* ctxbuf = (float*)alloc((size_t)NB * HID * 4);
    float* ctxo   = (float*)alloc((size_t)NB * LAT * 4);
    float* pgh    = (float*)alloc((size_t)NB * HID * 4);

    const size_t zbytes = (size_t)2 * NB * (LAT + HID) * 2
                        + (size_t)2 * NB * (2 * HID) * 2
                        + (size_t)NB * HID * 4 * 2;
    hipMemsetAsync(xh0, 0, zbytes, stream);

    const dim3 blk(256);
    const dim3 blk512(512);

    // ---- pack weights (gates: gate-interleaved + combined bias) ----
    {
        int tot = 4 * HID * (LAT + HID);
        pack_gates<<<dim3((tot + 255) / 256), blk, 0, stream>>>(
            w_ih0, LAT, w_hh0, HID, b_ih0, b_hh0, Wg0p, bc0, LAT + HID);
        tot = 4 * HID * (2 * HID);
        pack_gates<<<dim3((tot + 255) / 256), blk, 0, stream>>>(
            w_ih1, HID, w_hh1, HID, b_ih1, b_hh1, Wg1p, bc1, 2 * HID);
        tot = HID * HID;
        pack2<<<dim3((tot + 255) / 256), blk, 0, stream>>>(op_W1, HID, nullptr, 0, Wo1, tot, HID);
        tot = LAT * HID;
        pack2<<<dim3((tot + 255) / 256), blk, 0, stream>>>(op_W2, HID, nullptr, 0, Wo2, tot, HID);
    }

    // ---- prologue (fp32): attention read + prior ----
    gemm_tn<0><<<dim3(HID / 64, 1), blk, 0, stream>>>(
        mem, HID, k_W, HID, HID, nullptr, 0, nullptr, 0, 0,
        k_b, kbuf, HID, nullptr, 0, NSLOT, HID);
    gemm_tn<0><<<dim3(HID / 64, 1), blk, 0, stream>>>(
        mem, HID, v_W, HID, HID, nullptr, 0, nullptr, 0, 0,
        v_b, vbuf, HID, nullptr, 0, NSLOT, HID);
    gemm_tn<0><<<dim3(HID / 64, NB / 64), blk, 0, stream>>>(
        cs, LAT, q_W, LAT, LAT, nullptr, 0, nullptr, 0, 0,
        q_b, qbuf, HID, nullptr, 0, NB, HID);
    attn_kernel<<<dim3(NB), blk, 0, stream>>>(qbuf, kbuf, vbuf, ctxbuf);
    gemm_tn<0><<<dim3(LAT / 64, NB / 64), blk, 0, stream>>>(
        ctxbuf, HID, mo_W, HID, HID, nullptr, 0, nullptr, 0, 0,
        mo_b, ctxo, LAT, nullptr, 0, NB, LAT);
    gemm_tn<1><<<dim3(HID / 64, NB / 64), blk, 0, stream>>>(
        cs, LAT, pg_W1, HID, LAT, ctxo, LAT, pg_W1 + LAT, HID, LAT,
        pg_b1, pgh, HID, nullptr, 0, NB, HID);
    // prior -> fp32 output AND bf16 x0 into xh0 buffer 0 (first 512 cols)
    gemm_tn<0><<<dim3(LAT / 64, NB / 64), blk, 0, stream>>>(
        pgh, HID, pg_W2, HID, HID, nullptr, 0, nullptr, 0, 0,
        pg_b2, prior_out, LAT, xh0, LAT + HID, NB, LAT);

    // ---- LSTM rollout: 4 dispatches/step, pw fused, 2 K-teams per block ----
    for (int step = 0; step < HOR; ++step) {
        const int cur = step & 1, nxt = cur ^ 1;
        unsigned short* xh_r = xh0 + (size_t)cur * NB * (LAT + HID);
        unsigned short* xh_w = xh0 + (size_t)nxt * NB * (LAT + HID);
        unsigned short* hh_c = hh1 + (size_t)cur * NB * (2 * HID);
        unsigned short* hh_n = hh1 + (size_t)nxt * NB * (2 * HID);

        // gates0 + pw: h0 -> hh_c[:, :HID] (this step) AND xh_w[:, LAT:] (next step)
        mfma_gemm<64, 128, 3><<<dim3(4 * HID / 128, NB / 64), blk512, 0, stream>>>(
            xh_r, LAT + HID, Wg0p, LAT + HID, LAT + HID,
            bc0, c0, HID, hh_c, 2 * HID, xh_w + LAT, LAT + HID);
        // gates1 + pw: h1 -> hh_n[:, HID:] (read by op1 now, by gates1 next step)
        mfma_gemm<64, 128, 3><<<dim3(4 * HID / 128, NB / 64), blk512, 0, stream>>>(
            hh_c, 2 * HID, Wg1p, 2 * HID, 2 * HID,
            bc1, c1, HID, hh_n + HID, 2 * HID, nullptr, 0);
        // op1: t = relu(h1 @ Wo1^T + b1) -> tbuf (bf16)
        mfma_gemm<64, 64, 1><<<dim3(HID / 64, NB / 64), blk512, 0, stream>>>(
            hh_n + HID, 2 * HID, Wo1, HID, HID,
            op_b1, nullptr, 0, tbuf, HID, nullptr, 0);
        // op2: pred = t @ Wo2^T + b2 -> out[:,step,:] fp32 AND xh_w[:, :LAT] bf16
        mfma_gemm<64, 64, 2><<<dim3(LAT / 64, NB / 64), blk512, 0, stream>>>(
            tbuf, HID, Wo2, HID, HID,
            op_b2, out + (size_t)step * LAT, HOR * LAT, xh_w, LAT + HID, nullptr, 0);
    }
}